// Round 1
// baseline (23623.218 us; speedup 1.0000x reference)
//
#include <hip/hip_runtime.h>

// ============================================================================
// 2-layer LSTM, persistent kernel, MI355X.
// Design:
//   * 256 WGs x 512 threads (8 waves), exactly 1 WG/CU, all co-resident.
//   * Grid: wg_m = blk>>6 (4 M-tiles of 64 batch rows), wg_n = blk&63
//     (16 hidden units per layer per WG -> 64 gate rows/layer).
//   * Weights converted to bf16 fragments ONCE into registers:
//       B0[8][2]  : Wh0 slice (k-interleaved mod 4 across waves)
//       B1[12][2] : Wx1|Wh1 slice (first 12 of 16 ksteps; last 4 streamed)
//       B0x[2]    : Wx0 slice (x part, kway<2 only)
//   * Per phase t (513 phases): L0(t) and L1(t-1)  -> ONE grid barrier/phase.
//     A (h-tiles) staged to LDS in 256-k chunks, double-buffered, XOR-swizzled
//     (byte ^= (row&7)<<4) to kill the 16-way ds_read_b128 bank conflict.
//   * mfma_f32_16x16x32_bf16, wave tile m64 x n32, fp32 acc; k-split partials
//     reduced via 2-round LDS combine (gA/gB); EW (sigmoid/tanh) fused.
//   * c-state in LDS (persistent); h double-buffered bf16 in ws; h1 fp32 copy
//     written at t=511 for the fc epilogue.
//   * Custom 2-level grid barrier (per-XCD counters + root), agent-scope
//     atomics, plain launch (no cooperative API -> graph-capture safe).
// ============================================================================

typedef unsigned int u32;
typedef unsigned short u16;
typedef __attribute__((ext_vector_type(8))) short bf16x8;
typedef __attribute__((ext_vector_type(4))) float f32x4;

#define MFMA_BF16 __builtin_amdgcn_mfma_f32_16x16x32_bf16
#define HB (256 * 1024)   // h buffer elems per parity

__device__ __forceinline__ u16 f2bf(float f) {
  u32 u = __float_as_uint(f);
  u += 0x7fffu + ((u >> 16) & 1u);   // RNE (inputs finite)
  return (u16)(u >> 16);
}

__device__ __forceinline__ bf16x8 cvt8(const float* p) {
  bf16x8 r;
#pragma unroll
  for (int i = 0; i < 8; ++i) r[i] = (short)f2bf(p[i]);
  return r;
}

__device__ __forceinline__ float sigm(float v) { return 1.f / (1.f + __expf(-v)); }
__device__ __forceinline__ float tanhf_(float v) { return 1.f - 2.f / (__expf(2.f * v) + 1.f); }

// ---- MFMA tick macros (tk must be a literal so B-reg indices are static) ----
#define L0_TICK(tk, bsel) do {                                                  \
  _Pragma("unroll")                                                             \
  for (int jj = 0; jj < 2; ++jj) {                                              \
    const int j_ = 2 * ((tk) - 1) + jj;                                         \
    const int kin_ = (kway + (jj << 2)) << 5;                                   \
    _Pragma("unroll")                                                           \
    for (int mf = 0; mf < 4; ++mf) {                                            \
      bf16x8 a_ = readA(bsel, mf, kin_);                                        \
      acc[mf][0] = MFMA_BF16(a_, B0[j_][0], acc[mf][0], 0, 0, 0);               \
      acc[mf][1] = MFMA_BF16(a_, B0[j_][1], acc[mf][1], 0, 0, 0);               \
    }                                                                           \
  }                                                                             \
} while (0)

#define L1_TICK(tk, bsel) do {                                                  \
  _Pragma("unroll")                                                             \
  for (int jj = 0; jj < 2; ++jj) {                                              \
    const int j_ = 2 * (tk) + jj;                                               \
    const int kin_ = (kway + (jj << 2)) << 5;                                   \
    bf16x8 bq0_, bq1_;                                                          \
    if (j_ < 12) { bq0_ = B1[j_][0]; bq1_ = B1[j_][1]; }                        \
    else         { bq0_ = Wst[jj][0]; bq1_ = Wst[jj][1]; }                      \
    _Pragma("unroll")                                                           \
    for (int mf = 0; mf < 4; ++mf) {                                            \
      bf16x8 a_ = readA(bsel, mf, kin_);                                        \
      acc[mf][0] = MFMA_BF16(a_, bq0_, acc[mf][0], 0, 0, 0);                    \
      acc[mf][1] = MFMA_BF16(a_, bq1_, acc[mf][1], 0, 0, 0);                    \
    }                                                                           \
  }                                                                             \
} while (0)

__global__ void __launch_bounds__(512, 2)
lstm_persist(const float* __restrict__ x,
             const float* __restrict__ Wx0, const float* __restrict__ Wh0,
             const float* __restrict__ b0,
             const float* __restrict__ Wx1, const float* __restrict__ Wh1,
             const float* __restrict__ b1,
             const float* __restrict__ fcW, const float* __restrict__ fcb,
             u16* __restrict__ h0b, u16* __restrict__ h1b,
             float* __restrict__ h1f, u32* __restrict__ bar,
             float* __restrict__ out)
{
  const int tid = threadIdx.x, blk = blockIdx.x;
  const int lane = tid & 63, w = tid >> 6;
  const int s = w >> 2;        // n32 slice 0/1
  const int kway = w & 3;      // k-interleave lane (ksteps with kk%4==kway)
  const int m0 = (blk >> 6) << 6;   // batch tile base (4 tiles of 64)
  const int u0 = (blk & 63) << 4;   // hidden-unit base (16 units/layer)

  __shared__ short Abuf[2][64 * 256];   // 2 x 32KB A chunks (64 rows x 256 bf16)
  __shared__ float gA[64][68];          // k-reduce region A (pad 68 vs banks)
  __shared__ float gB[64][68];          // k-reduce region B
  __shared__ float cbuf[2][64][16];     // persistent c state, both layers

  for (int i = tid; i < 2 * 64 * 16; i += 512) ((float*)cbuf)[i] = 0.f;

  const int i15 = lane & 15, kq = lane >> 4;

  // gate-row mapping: frag f covers gates {2f, 2f+1}; lane i15:
  //   gate = 2f + (i15>>3), unit = u0 + s*8 + (i15&7)
  int rowf[2];
#pragma unroll
  for (int f = 0; f < 2; ++f)
    rowf[f] = ((f << 1) + (i15 >> 3)) * 1024 + u0 + s * 8 + (i15 & 7);

  // ---------------- B preload (one-time f32 -> bf16 regs) ----------------
  bf16x8 B0[8][2], B1[12][2], B0x[2], Wst[2][2];
#pragma unroll
  for (int j = 0; j < 8; ++j)
#pragma unroll
    for (int f = 0; f < 2; ++f)
      B0[j][f] = cvt8(Wh0 + (size_t)rowf[f] * 1024 + (kway + 4 * j) * 32 + kq * 8);
#pragma unroll
  for (int j = 0; j < 12; ++j)
#pragma unroll
    for (int f = 0; f < 2; ++f) {
      int k = (kway + 4 * j) * 32 + kq * 8;
      B1[j][f] = (k < 1024) ? cvt8(Wx1 + (size_t)rowf[f] * 1024 + k)
                            : cvt8(Wh1 + (size_t)rowf[f] * 1024 + (k - 1024));
    }
  if (kway < 2) {   // x-part ksteps (kk=0,1) owned by kway 0/1 only
#pragma unroll
    for (int f = 0; f < 2; ++f)
      B0x[f] = cvt8(Wx0 + (size_t)rowf[f] * 64 + kway * 32 + kq * 8);
  }

  float bias0[2], bias1[2];
#pragma unroll
  for (int f = 0; f < 2; ++f) {
    bias0[f] = (kway == 0) ? b0[rowf[f]] : 0.f;   // bias only in one partial!
    bias1[f] = (kway == 0) ? b1[rowf[f]] : 0.f;
  }

  // ---------------- helpers ----------------
  // stage 64 rows x 256 bf16 chunk: linear global read, XOR-swizzled LDS write
  auto stage_h = [&](int bsel, const u16* src, int kbase) {
#pragma unroll
    for (int cc = 0; cc < 4; ++cc) {
      int call = (w << 2) | cc;
      int row = (call << 1) | (lane >> 5);
      int c = lane & 31;
      const u16* g = src + ((size_t)(m0 + row) << 10) + kbase + (c << 3);
      bf16x8 v = *(const bf16x8*)g;
      *(bf16x8*)&Abuf[bsel][(row << 8) + ((c ^ (row & 7)) << 3)] = v;
    }
  };

  auto stage_x = [&](int t) {   // x tile 64x64, f32 -> bf16, into Abuf[0]
    int row = tid >> 3, c = tid & 7;
    const float* g = x + ((size_t)(m0 + row) * 512 + t) * 64 + (c << 3);
    float4 v0 = *(const float4*)g;
    float4 v1 = *(const float4*)(g + 4);
    bf16x8 r;
    r[0] = (short)f2bf(v0.x); r[1] = (short)f2bf(v0.y);
    r[2] = (short)f2bf(v0.z); r[3] = (short)f2bf(v0.w);
    r[4] = (short)f2bf(v1.x); r[5] = (short)f2bf(v1.y);
    r[6] = (short)f2bf(v1.z); r[7] = (short)f2bf(v1.w);
    *(bf16x8*)&Abuf[0][(row << 8) + ((c ^ (row & 7)) << 3)] = r;
  };

  auto readA = [&](int bsel, int mf, int kin) -> bf16x8 {
    int row = (mf << 4) | i15;
    int c = ((kin >> 3) + kq) ^ (row & 7);
    return *(const bf16x8*)&Abuf[bsel][(row << 8) + (c << 3)];
  };

  f32x4 acc[4][2];

  auto acc_init = [&](const float* bias) {
#pragma unroll
    for (int mf = 0; mf < 4; ++mf)
#pragma unroll
      for (int f = 0; f < 2; ++f) {
        acc[mf][f][0] = bias[f]; acc[mf][f][1] = bias[f];
        acc[mf][f][2] = bias[f]; acc[mf][f][3] = bias[f];
      }
  };

  auto reduce2 = [&]() {   // 2-round k-partial combine into gA/gB
    if (kway < 2) {
      float (*g)[68] = kway ? gB : gA;
#pragma unroll
      for (int mf = 0; mf < 4; ++mf)
#pragma unroll
        for (int f = 0; f < 2; ++f)
#pragma unroll
          for (int r = 0; r < 4; ++r)
            g[(mf << 4) + (kq << 2) + r][(s << 5) + (f << 4) + i15] = acc[mf][f][r];
    }
    __syncthreads();
    if (kway >= 2) {
      float (*g)[68] = (kway == 3) ? gB : gA;
#pragma unroll
      for (int mf = 0; mf < 4; ++mf)
#pragma unroll
        for (int f = 0; f < 2; ++f)
#pragma unroll
          for (int r = 0; r < 4; ++r)
            g[(mf << 4) + (kq << 2) + r][(s << 5) + (f << 4) + i15] += acc[mf][f][r];
    }
    __syncthreads();
  };

  auto ew = [&](int L, u16* hdst, bool wf32) {
#pragma unroll
    for (int e0 = 0; e0 < 2; ++e0) {
      int e = tid + (e0 << 9);                    // 0..1023
      int row = e >> 4, un = e & 15;
      int cb = ((un >> 3) << 5) | (un & 7);       // gate g at cb + 8*g
      float gi = gA[row][cb]      + gB[row][cb];
      float gf = gA[row][cb + 8]  + gB[row][cb + 8];
      float gg = gA[row][cb + 16] + gB[row][cb + 16];
      float go = gA[row][cb + 24] + gB[row][cb + 24];
      float ii = sigm(gi), ff = sigm(gf), g2 = tanhf_(gg), oo = sigm(go);
      float c = ff * cbuf[L][row][un] + ii * g2;
      cbuf[L][row][un] = c;
      float h = oo * tanhf_(c);
      size_t idx = ((size_t)(m0 + row) << 10) + u0 + un;
      hdst[idx] = f2bf(h);
      if (wf32) h1f[idx] = h;
    }
  };

  auto loadWst = [&](int jb) {   // streamed Wh1 tail frags (j = jb, jb+1)
#pragma unroll
    for (int jj = 0; jj < 2; ++jj)
#pragma unroll
      for (int f = 0; f < 2; ++f) {
        int k = (kway + ((jb + jj) << 2)) * 32 + (kq << 3) - 1024;
        Wst[jj][f] = cvt8(Wh1 + (size_t)rowf[f] * 1024 + k);
      }
  };

  // ---------------- phase loop: phase t = { L0(t), L1(t-1) } ----------------
#pragma unroll 1
  for (int t = 0; t <= 512; ++t) {
    const u16* h0rd = h0b + ((t + 1) & 1) * HB;   // h0(t-1)
    u16* h0wr = h0b + (t & 1) * HB;               // h0(t)
    const u16* h1rd = h1b + (t & 1) * HB;         // h1(t-2)
    u16* h1wr = h1b + ((t + 1) & 1) * HB;         // h1(t-1)
    const bool doL0 = (t < 512), doL1 = (t >= 1);

    if (doL0) {
      acc_init(bias0);
      stage_x(t);
      __syncthreads();
      // tick 0: x kstep(s) + stage h0 chunk0
      stage_h(1, h0rd, 0);
      if (kway < 2) {
        const int kin = kway << 5;
#pragma unroll
        for (int mf = 0; mf < 4; ++mf) {
          bf16x8 a = readA(0, mf, kin);
          acc[mf][0] = MFMA_BF16(a, B0x[0], acc[mf][0], 0, 0, 0);
          acc[mf][1] = MFMA_BF16(a, B0x[1], acc[mf][1], 0, 0, 0);
        }
      }
      __syncthreads();
      stage_h(0, h0rd, 256);  L0_TICK(1, 1); __syncthreads();
      stage_h(1, h0rd, 512);  L0_TICK(2, 0); __syncthreads();
      stage_h(0, h0rd, 768);  L0_TICK(3, 1); __syncthreads();
      if (doL1) stage_h(1, h0rd, 0);          // L1 chunk0 prefetch
      L0_TICK(4, 0); __syncthreads();
      reduce2();
      ew(0, h0wr, false);
    } else {
      stage_h(1, h0rd, 0);    // t==512: only prep L1 chunk0
      __syncthreads();
    }

    if (doL1) {
      acc_init(bias1);
      stage_h(0, h0rd, 256);  L1_TICK(0, 1); __syncthreads();
      stage_h(1, h0rd, 512);  L1_TICK(1, 0); __syncthreads();
      stage_h(0, h0rd, 768);  L1_TICK(2, 1); __syncthreads();
      stage_h(1, h1rd, 0);    L1_TICK(3, 0); __syncthreads();
      stage_h(0, h1rd, 256);  L1_TICK(4, 1); __syncthreads();
      stage_h(1, h1rd, 512);  L1_TICK(5, 0); loadWst(12); __syncthreads();
      stage_h(0, h1rd, 768);  L1_TICK(6, 1); loadWst(14); __syncthreads();
      L1_TICK(7, 0); __syncthreads();
      reduce2();
      ew(1, h1wr, t == 512);
    }

    // ---- grid barrier: two-level (8 XCD-groups -> root), agent scope ----
    __syncthreads();
    if (tid == 0) {
      const int g = blk & 7;
      u32* gc   = bar + g * 32;
      u32* root = bar + 256;
      u32* gen  = bar + 288 + g * 32;
      const u32 p1 = (u32)(t + 1);
      __hip_atomic_fetch_add(gc, 1u, __ATOMIC_ACQ_REL, __HIP_MEMORY_SCOPE_AGENT);
      if ((blk >> 3) == 0) {   // leader of group g (block g)
        while (__hip_atomic_load(gc, __ATOMIC_ACQUIRE, __HIP_MEMORY_SCOPE_AGENT) < 32u * p1) {}
        __hip_atomic_fetch_add(root, 1u, __ATOMIC_ACQ_REL, __HIP_MEMORY_SCOPE_AGENT);
        while (__hip_atomic_load(root, __ATOMIC_ACQUIRE, __HIP_MEMORY_SCOPE_AGENT) < 8u * p1) {}
        __hip_atomic_store(gen, p1, __ATOMIC_RELEASE, __HIP_MEMORY_SCOPE_AGENT);
      } else {
        while (__hip_atomic_load(gen, __ATOMIC_ACQUIRE, __HIP_MEMORY_SCOPE_AGENT) < p1) {}
      }
    }
    __syncthreads();
  }

  // ---------------- fc epilogue: out = h1(511) @ fcW.T + fcb ----------------
  if (blk < 32) {
    const int row = (blk << 3) | w;              // one batch row per wave
    const float* hrow = h1f + ((size_t)row << 10);
#pragma unroll 1
    for (int o = 0; o < 12; ++o) {
      const float* wrow = fcW + o * 1024;
      float p = 0.f;
#pragma unroll
      for (int j = 0; j < 16; ++j) {
        int k = (j << 6) | lane;
        p += hrow[k] * wrow[k];
      }
#pragma unroll
      for (int off = 32; off > 0; off >>= 1) p += __shfl_down(p, off, 64);
      if (lane == 0) out[row * 12 + o] = p + fcb[o];
    }
  }
}

extern "C" void kernel_launch(void* const* d_in, const int* in_sizes, int n_in,
                              void* d_out, int out_size, void* d_ws, size_t ws_size,
                              hipStream_t stream) {
  (void)in_sizes; (void)n_in; (void)out_size; (void)ws_size;
  const float* x   = (const float*)d_in[0];
  const float* Wx0 = (const float*)d_in[1];
  const float* Wh0 = (const float*)d_in[2];
  const float* b0  = (const float*)d_in[3];
  const float* Wx1 = (const float*)d_in[4];
  const float* Wh1 = (const float*)d_in[5];
  const float* b1  = (const float*)d_in[6];
  const float* fcW = (const float*)d_in[7];
  const float* fcb = (const float*)d_in[8];

  char* ws = (char*)d_ws;
  u16* h0b   = (u16*)ws;                    // 2 x 512 KiB (parity buffers)
  u16* h1b   = (u16*)(ws + (1 << 20));      // 2 x 512 KiB
  float* h1f = (float*)(ws + (2 << 20));    // 1 MiB fp32 final h1
  u32* bar   = (u32*)(ws + (3 << 20));      // barrier counters

  // zero initial-state parities + barrier counters (every launch: ws is not
  // re-poisoned between replays and the barrier counter must restart at 0)
  hipMemsetAsync(ws + (1 << 19), 0, 1 << 19, stream);               // h0b[1]
  hipMemsetAsync(ws + (1 << 20) + (1 << 19), 0, 1 << 19, stream);   // h1b[1]
  hipMemsetAsync(bar, 0, 4096, stream);

  lstm_persist<<<256, 512, 0, stream>>>(x, Wx0, Wh0, b0, Wx1, Wh1, b1,
                                        fcW, fcb, h0b, h1b, h1f, bar,
                                        (float*)d_out);
}